// Round 1
// baseline (1196.520 us; speedup 1.0000x reference)
//
#include <hip/hip_runtime.h>
#include <stdint.h>

using u16 = unsigned short;
using u32 = unsigned int;

typedef __attribute__((ext_vector_type(8))) short s16x8;
typedef __attribute__((ext_vector_type(4))) float f32x4;

__device__ __forceinline__ float bflo(u32 u) { u32 t = u << 16; float f; __builtin_memcpy(&f, &t, 4); return f; }
__device__ __forceinline__ float bfhi(u32 u) { u32 t = u & 0xffff0000u; float f; __builtin_memcpy(&f, &t, 4); return f; }
__device__ __forceinline__ u16 f2bf(float f) {
  u32 u; __builtin_memcpy(&u, &f, 4);
  return (u16)((u + 0x7fffu + ((u >> 16) & 1u)) >> 16);
}

__device__ __forceinline__ void gload_lds16(const void* g, void* l) {
  __builtin_amdgcn_global_load_lds((const __attribute__((address_space(1))) void*)g,
                                   (__attribute__((address_space(3))) void*)l, 16, 0, 0);
}

// ---------------- transpose + fp32->bf16 pack: in [R][Cc] -> out [Cc][R] ----------------
__global__ __launch_bounds__(256)
void transpose_pack(const float* __restrict__ in, u16* __restrict__ out,
                    int R, int Cc, long in_bs, long out_bs)
{
  __shared__ float tile[32][33];
  in  += (size_t)blockIdx.z * in_bs;
  out += (size_t)blockIdx.z * out_bs;
  const int r0 = blockIdx.x * 32, c0 = blockIdx.y * 32;
  const int tx = threadIdx.x & 31, ty = threadIdx.x >> 5;   // 32 x 8
#pragma unroll
  for (int i = 0; i < 4; ++i) {
    int r = ty + i * 8;
    tile[r][tx] = in[(size_t)(r0 + r) * Cc + c0 + tx];
  }
  __syncthreads();
#pragma unroll
  for (int i = 0; i < 4; ++i) {
    int c = ty + i * 8;
    out[(size_t)(c0 + c) * R + r0 + tx] = f2bf(tile[tx][c]);
  }
}

// ---------------- LayerNorm fp32 -> bf16, C=1024, one block per row ----------------
__global__ __launch_bounds__(256)
void ln_f32_bf16(const float* __restrict__ x, const float* __restrict__ g,
                 const float* __restrict__ bta, u16* __restrict__ out)
{
  const int row = blockIdx.x, tid = threadIdx.x;
  const float4 v = ((const float4*)(x + (size_t)row * 1024))[tid];
  float s  = v.x + v.y + v.z + v.w;
  float ss = v.x * v.x + v.y * v.y + v.z * v.z + v.w * v.w;
#pragma unroll
  for (int m = 1; m < 64; m <<= 1) {
    s  += __shfl_xor(s, m);
    ss += __shfl_xor(ss, m);
  }
  __shared__ float red[8];
  const int wave = tid >> 6, lane = tid & 63;
  if (lane == 0) { red[wave] = s; red[4 + wave] = ss; }
  __syncthreads();
  s  = red[0] + red[1] + red[2] + red[3];
  ss = red[4] + red[5] + red[6] + red[7];
  const float mu  = s * (1.f / 1024.f);
  const float var = ss * (1.f / 1024.f) - mu * mu;
  const float rs  = rsqrtf(var + 1e-5f);
  const float4 gg = ((const float4*)g)[tid];
  const float4 bb = ((const float4*)bta)[tid];
  u32 w0 = (u32)f2bf((v.x - mu) * rs * gg.x + bb.x) | ((u32)f2bf((v.y - mu) * rs * gg.y + bb.y) << 16);
  u32 w1 = (u32)f2bf((v.z - mu) * rs * gg.z + bb.z) | ((u32)f2bf((v.w - mu) * rs * gg.w + bb.w) << 16);
  u32* outp = (u32*)(out + (size_t)row * 1024 + tid * 4);
  outp[0] = w0; outp[1] = w1;
}

// ---------------- GEMM: A[M][K] bf16 row-major, B[N][K] bf16 (transposed), m97 structure ----
// EPI 0: C=bf16(acc)            (QKV)
// EPI 1: C=f32 acc+bias+resid   (attn proj + residual)
// EPI 2: C=bf16 relu(acc+bias)  (FFN1)
// EPI 3: C=f32 acc+bias+resid   (FFN2 -> d_out)
template <int EPI>
__global__ __launch_bounds__(256)
void gemm_bt(const u16* __restrict__ A, const u16* __restrict__ B, void* __restrict__ Cv,
             const float* __restrict__ bias, const float* __restrict__ resid,
             int M, int N, int K)
{
  constexpr int BM = 128, BN = 128, BK = 64;
  __shared__ u16 As[BM * BK];
  __shared__ u16 Bs[BN * BK];
  const int tid  = threadIdx.x;
  const int lane = tid & 63, wave = tid >> 6;
  const int wr = wave >> 1, wc = wave & 1;          // 2x2 wave grid, 64x64 each
  const int bm = blockIdx.x, bn = blockIdx.y;
  const u16* Ab = A + (size_t)bm * BM * K;
  const u16* Bb = B + (size_t)bn * BN * K;
  const int r = lane & 15, kg = lane >> 4;

  f32x4 acc[4][4];
#pragma unroll
  for (int m = 0; m < 4; ++m)
#pragma unroll
    for (int n = 0; n < 4; ++n) acc[m][n] = f32x4{0.f, 0.f, 0.f, 0.f};

  for (int k0 = 0; k0 < K; k0 += BK) {
#pragma unroll
    for (int j = 0; j < 4; ++j) {
      int ci = j * 256 + tid;
      int row = ci >> 3, c8 = (ci & 7) << 3;
      gload_lds16(Ab + (size_t)row * K + (k0 + c8), &As[ci * 8]);
    }
#pragma unroll
    for (int j = 0; j < 4; ++j) {
      int ci = j * 256 + tid;
      int row = ci >> 3, c8 = (ci & 7) << 3;
      gload_lds16(Bb + (size_t)row * K + (k0 + c8), &Bs[ci * 8]);
    }
    __syncthreads();
#pragma unroll
    for (int kk = 0; kk < BK; kk += 32) {
      s16x8 af[4], bfr[4];
#pragma unroll
      for (int m = 0; m < 4; ++m)
        af[m] = *(const s16x8*)&As[(wr * 64 + m * 16 + r) * BK + kk + kg * 8];
#pragma unroll
      for (int n = 0; n < 4; ++n)
        bfr[n] = *(const s16x8*)&Bs[(wc * 64 + n * 16 + r) * BK + kk + kg * 8];
#pragma unroll
      for (int m = 0; m < 4; ++m)
#pragma unroll
        for (int n = 0; n < 4; ++n)
          acc[m][n] = __builtin_amdgcn_mfma_f32_16x16x32_bf16(af[m], bfr[n], acc[m][n], 0, 0, 0);
    }
    __syncthreads();
  }

#pragma unroll
  for (int m = 0; m < 4; ++m) {
#pragma unroll
    for (int n = 0; n < 4; ++n) {
#pragma unroll
      for (int j = 0; j < 4; ++j) {
        int row = bm * BM + wr * 64 + m * 16 + kg * 4 + j;
        int col = bn * BN + wc * 64 + n * 16 + r;
        size_t idx = (size_t)row * N + col;
        float v = acc[m][n][j];
        if constexpr (EPI == 0) {
          ((u16*)Cv)[idx] = f2bf(v);
        } else if constexpr (EPI == 1) {
          ((float*)Cv)[idx] = v + bias[col] + resid[idx];
        } else if constexpr (EPI == 2) {
          ((u16*)Cv)[idx] = f2bf(fmaxf(v + bias[col], 0.f));
        } else {
          ((float*)Cv)[idx] = v + bias[col] + resid[idx];
        }
      }
    }
  }
}

// ---------------- scalar flash attention: one block per (b,h), thread t = query row ----------
// qkv [B*T][3072] bf16 (cols: 0..1023 Q | 1024..2047 K | 2048..3071 V, per-head 64 chunks)
__global__ __launch_bounds__(256)
void attn_flash(const u16* __restrict__ qkv, u16* __restrict__ outc)
{
  const int bh = blockIdx.x, b = bh >> 4, h = bh & 15;
  const int t = threadIdx.x;
  __shared__ u16 Ks[256 * 64];
  __shared__ u16 Vs[256 * 64];
  const u16* rowp = qkv + (size_t)(b * 256 + t) * 3072 + h * 64;

  const uint4* kp4 = (const uint4*)(rowp + 1024);
  const uint4* vp4 = (const uint4*)(rowp + 2048);
  uint4* ksd = (uint4*)&Ks[t * 64];
  uint4* vsd = (uint4*)&Vs[t * 64];
#pragma unroll
  for (int j = 0; j < 8; ++j) ksd[j] = kp4[j];
#pragma unroll
  for (int j = 0; j < 8; ++j) vsd[j] = vp4[j];

  float q[64];
  const uint4* qp4 = (const uint4*)rowp;
#pragma unroll
  for (int j = 0; j < 8; ++j) {
    uint4 u = qp4[j];
    q[j * 8 + 0] = bflo(u.x) * 0.03125f; q[j * 8 + 1] = bfhi(u.x) * 0.03125f;
    q[j * 8 + 2] = bflo(u.y) * 0.03125f; q[j * 8 + 3] = bfhi(u.y) * 0.03125f;
    q[j * 8 + 4] = bflo(u.z) * 0.03125f; q[j * 8 + 5] = bfhi(u.z) * 0.03125f;
    q[j * 8 + 6] = bflo(u.w) * 0.03125f; q[j * 8 + 7] = bfhi(u.w) * 0.03125f;
  }
  __syncthreads();

  float mrun = -INFINITY, lrun = 0.f;
  float o[64];
#pragma unroll
  for (int d = 0; d < 64; ++d) o[d] = 0.f;

  for (int s = 0; s <= t; ++s) {
    const uint4* kr = (const uint4*)&Ks[s * 64];
    float a0 = 0.f, a1 = 0.f, a2 = 0.f, a3 = 0.f, a4 = 0.f, a5 = 0.f, a6 = 0.f, a7 = 0.f;
#pragma unroll
    for (int jj = 0; jj < 8; ++jj) {
      uint4 u = kr[jj];
      a0 = fmaf(q[jj * 8 + 0], bflo(u.x), a0); a1 = fmaf(q[jj * 8 + 1], bfhi(u.x), a1);
      a2 = fmaf(q[jj * 8 + 2], bflo(u.y), a2); a3 = fmaf(q[jj * 8 + 3], bfhi(u.y), a3);
      a4 = fmaf(q[jj * 8 + 4], bflo(u.z), a4); a5 = fmaf(q[jj * 8 + 5], bfhi(u.z), a5);
      a6 = fmaf(q[jj * 8 + 6], bflo(u.w), a6); a7 = fmaf(q[jj * 8 + 7], bfhi(u.w), a7);
    }
    float sc = ((a0 + a1) + (a2 + a3)) + ((a4 + a5) + (a6 + a7));
    const uint4* vr = (const uint4*)&Vs[s * 64];
    if (sc <= mrun) {
      float p = exp2f((sc - mrun) * 1.4426950408889634f);
      lrun += p;
#pragma unroll
      for (int jj = 0; jj < 8; ++jj) {
        uint4 u = vr[jj];
        o[jj * 8 + 0] = fmaf(p, bflo(u.x), o[jj * 8 + 0]); o[jj * 8 + 1] = fmaf(p, bfhi(u.x), o[jj * 8 + 1]);
        o[jj * 8 + 2] = fmaf(p, bflo(u.y), o[jj * 8 + 2]); o[jj * 8 + 3] = fmaf(p, bfhi(u.y), o[jj * 8 + 3]);
        o[jj * 8 + 4] = fmaf(p, bflo(u.z), o[jj * 8 + 4]); o[jj * 8 + 5] = fmaf(p, bfhi(u.z), o[jj * 8 + 5]);
        o[jj * 8 + 6] = fmaf(p, bflo(u.w), o[jj * 8 + 6]); o[jj * 8 + 7] = fmaf(p, bfhi(u.w), o[jj * 8 + 7]);
      }
    } else {
      float rsc = exp2f((mrun - sc) * 1.4426950408889634f);
      lrun = fmaf(lrun, rsc, 1.f);
#pragma unroll
      for (int jj = 0; jj < 8; ++jj) {
        uint4 u = vr[jj];
        o[jj * 8 + 0] = fmaf(o[jj * 8 + 0], rsc, bflo(u.x)); o[jj * 8 + 1] = fmaf(o[jj * 8 + 1], rsc, bfhi(u.x));
        o[jj * 8 + 2] = fmaf(o[jj * 8 + 2], rsc, bflo(u.y)); o[jj * 8 + 3] = fmaf(o[jj * 8 + 3], rsc, bfhi(u.y));
        o[jj * 8 + 4] = fmaf(o[jj * 8 + 4], rsc, bflo(u.z)); o[jj * 8 + 5] = fmaf(o[jj * 8 + 5], rsc, bfhi(u.z));
        o[jj * 8 + 6] = fmaf(o[jj * 8 + 6], rsc, bflo(u.w)); o[jj * 8 + 7] = fmaf(o[jj * 8 + 7], rsc, bfhi(u.w));
      }
      mrun = sc;
    }
  }
  float inv = 1.f / lrun;
  u32* op = (u32*)(outc + (size_t)(b * 256 + t) * 1024 + h * 64);
#pragma unroll
  for (int i = 0; i < 32; ++i) {
    u16 lo = f2bf(o[2 * i] * inv), hi = f2bf(o[2 * i + 1] * inv);
    op[i] = (u32)lo | ((u32)hi << 16);
  }
}

// ------------------------------------------------------------------------------------------
extern "C" void kernel_launch(void* const* d_in, const int* in_sizes, int n_in,
                              void* d_out, int out_size, void* d_ws, size_t ws_size,
                              hipStream_t stream) {
  (void)in_sizes; (void)n_in; (void)out_size; (void)ws_size;
  const float* x     = (const float*)d_in[0];
  const float* Wq    = (const float*)d_in[1];
  const float* Wk    = (const float*)d_in[2];
  const float* Wv    = (const float*)d_in[3];
  const float* Wproj = (const float*)d_in[4];
  const float* bproj = (const float*)d_in[5];
  const float* W1    = (const float*)d_in[6];
  const float* b1    = (const float*)d_in[7];
  const float* W2    = (const float*)d_in[8];
  const float* b2    = (const float*)d_in[9];
  const float* ln1g  = (const float*)d_in[10];
  const float* ln1b  = (const float*)d_in[11];
  const float* ln2g  = (const float*)d_in[12];
  const float* ln2b  = (const float*)d_in[13];
  float* out = (float*)d_out;

  char* ws = (char*)d_ws;
  u16*   WqkvT  = (u16*)(ws + 0);              // [3072][1024] bf16
  u16*   WprojT = (u16*)(ws + 6291456);        // [1024][1024]
  u16*   W1T    = (u16*)(ws + 8388608);        // [4096][1024]
  u16*   W2T    = (u16*)(ws + 16777216);       // [1024][4096]
  u16*   hb     = (u16*)(ws + 25165824);       // [16384][1024] LN1 out; later reused as attnout
  u16*   qkvb   = (u16*)(ws + 58720256);       // [16384][3072]
  float* x2     = (float*)(ws + 159383552);    // [16384][1024] f32
  u16*   h2     = (u16*)(ws + 226492416);      // [16384][1024]
  u16*   ffn1   = (u16*)(ws + 25165824);       // [16384][4096] overlays hb+qkvb (both dead by then)
  u16*   attnout = hb;

  const int M = 16384;

  // weight packs (transpose to [N][K] bf16)
  transpose_pack<<<dim3(32, 2, 16), 256, 0, stream>>>(Wq, WqkvT,           1024, 64, 65536, 65536);
  transpose_pack<<<dim3(32, 2, 16), 256, 0, stream>>>(Wk, WqkvT + 1048576, 1024, 64, 65536, 65536);
  transpose_pack<<<dim3(32, 2, 16), 256, 0, stream>>>(Wv, WqkvT + 2097152, 1024, 64, 65536, 65536);
  transpose_pack<<<dim3(32, 32, 1), 256, 0, stream>>>(Wproj, WprojT, 1024, 1024, 0, 0);
  transpose_pack<<<dim3(32, 128, 1), 256, 0, stream>>>(W1, W1T, 1024, 4096, 0, 0);
  transpose_pack<<<dim3(128, 32, 1), 256, 0, stream>>>(W2, W2T, 4096, 1024, 0, 0);

  // LN1
  ln_f32_bf16<<<M, 256, 0, stream>>>(x, ln1g, ln1b, hb);

  // QKV fused GEMM: [16384,1024] x [3072,1024]^T -> [16384,3072] bf16
  gemm_bt<0><<<dim3(M / 128, 24), 256, 0, stream>>>(hb, WqkvT, qkvb, nullptr, nullptr, M, 3072, 1024);

  // attention -> attnout [16384][1024] bf16 (concat heads)
  attn_flash<<<1024, 256, 0, stream>>>(qkvb, attnout);

  // proj + bias + residual(x) -> x2 f32
  gemm_bt<1><<<dim3(M / 128, 8), 256, 0, stream>>>(attnout, WprojT, x2, bproj, x, M, 1024, 1024);

  // LN2
  ln_f32_bf16<<<M, 256, 0, stream>>>(x2, ln2g, ln2b, h2);

  // FFN1: relu(h2 @ W1 + b1) -> ffn1 bf16 [16384][4096]
  gemm_bt<2><<<dim3(M / 128, 32), 256, 0, stream>>>(h2, W1T, ffn1, b1, nullptr, M, 4096, 1024);

  // FFN2: ffn1 @ W2 + b2 + x2 -> out f32
  gemm_bt<3><<<dim3(M / 128, 8), 256, 0, stream>>>(ffn1, W2T, out, b2, x2, M, 1024, 4096);
}

// Round 2
// 880.303 us; speedup vs baseline: 1.3592x; 1.3592x over previous
//
#include <hip/hip_runtime.h>
#include <stdint.h>

using u16 = unsigned short;
using u32 = unsigned int;

typedef __attribute__((ext_vector_type(8))) short s16x8;
typedef __attribute__((ext_vector_type(4))) float f32x4;

__device__ __forceinline__ float bflo(u32 u) { u32 t = u << 16; float f; __builtin_memcpy(&f, &t, 4); return f; }
__device__ __forceinline__ float bfhi(u32 u) { u32 t = u & 0xffff0000u; float f; __builtin_memcpy(&f, &t, 4); return f; }
__device__ __forceinline__ u16 f2bf(float f) {
  u32 u; __builtin_memcpy(&u, &f, 4);
  return (u16)((u + 0x7fffu + ((u >> 16) & 1u)) >> 16);
}

__device__ __forceinline__ void gload_lds16(const void* g, void* l) {
  __builtin_amdgcn_global_load_lds((const __attribute__((address_space(1))) void*)g,
                                   (__attribute__((address_space(3))) void*)l, 16, 0, 0);
}

// ---------------- transpose + fp32->bf16 pack: in [R][Cc] -> out [Cc][R] ----------------
__global__ __launch_bounds__(256)
void transpose_pack(const float* __restrict__ in, u16* __restrict__ out,
                    int R, int Cc, long in_bs, long out_bs)
{
  __shared__ float tile[32][33];
  in  += (size_t)blockIdx.z * in_bs;
  out += (size_t)blockIdx.z * out_bs;
  const int r0 = blockIdx.x * 32, c0 = blockIdx.y * 32;
  const int tx = threadIdx.x & 31, ty = threadIdx.x >> 5;   // 32 x 8
#pragma unroll
  for (int i = 0; i < 4; ++i) {
    int r = ty + i * 8;
    tile[r][tx] = in[(size_t)(r0 + r) * Cc + c0 + tx];
  }
  __syncthreads();
#pragma unroll
  for (int i = 0; i < 4; ++i) {
    int c = ty + i * 8;
    out[(size_t)(c0 + c) * R + r0 + tx] = f2bf(tile[tx][c]);
  }
}

// ---------------- LayerNorm fp32 -> bf16, C=1024, one block per row ----------------
__global__ __launch_bounds__(256)
void ln_f32_bf16(const float* __restrict__ x, const float* __restrict__ g,
                 const float* __restrict__ bta, u16* __restrict__ out)
{
  const int row = blockIdx.x, tid = threadIdx.x;
  const float4 v = ((const float4*)(x + (size_t)row * 1024))[tid];
  float s  = v.x + v.y + v.z + v.w;
  float ss = v.x * v.x + v.y * v.y + v.z * v.z + v.w * v.w;
#pragma unroll
  for (int m = 1; m < 64; m <<= 1) {
    s  += __shfl_xor(s, m);
    ss += __shfl_xor(ss, m);
  }
  __shared__ float red[8];
  const int wave = tid >> 6, lane = tid & 63;
  if (lane == 0) { red[wave] = s; red[4 + wave] = ss; }
  __syncthreads();
  s  = red[0] + red[1] + red[2] + red[3];
  ss = red[4] + red[5] + red[6] + red[7];
  const float mu  = s * (1.f / 1024.f);
  const float var = ss * (1.f / 1024.f) - mu * mu;
  const float rs  = rsqrtf(var + 1e-5f);
  const float4 gg = ((const float4*)g)[tid];
  const float4 bb = ((const float4*)bta)[tid];
  u32 w0 = (u32)f2bf((v.x - mu) * rs * gg.x + bb.x) | ((u32)f2bf((v.y - mu) * rs * gg.y + bb.y) << 16);
  u32 w1 = (u32)f2bf((v.z - mu) * rs * gg.z + bb.z) | ((u32)f2bf((v.w - mu) * rs * gg.w + bb.w) << 16);
  u32* outp = (u32*)(out + (size_t)row * 1024 + tid * 4);
  outp[0] = w0; outp[1] = w1;
}

// ---------------- GEMM: A[M][K] bf16 row-major, B[N][K] bf16 (transposed), m97 structure ----
template <int EPI>
__global__ __launch_bounds__(256)
void gemm_bt(const u16* __restrict__ A, const u16* __restrict__ B, void* __restrict__ Cv,
             const float* __restrict__ bias, const float* __restrict__ resid,
             int M, int N, int K)
{
  constexpr int BM = 128, BN = 128, BK = 64;
  __shared__ u16 As[BM * BK];
  __shared__ u16 Bs[BN * BK];
  const int tid  = threadIdx.x;
  const int lane = tid & 63, wave = tid >> 6;
  const int wr = wave >> 1, wc = wave & 1;          // 2x2 wave grid, 64x64 each
  const int bm = blockIdx.x, bn = blockIdx.y;
  const u16* Ab = A + (size_t)bm * BM * K;
  const u16* Bb = B + (size_t)bn * BN * K;
  const int r = lane & 15, kg = lane >> 4;

  f32x4 acc[4][4];
#pragma unroll
  for (int m = 0; m < 4; ++m)
#pragma unroll
    for (int n = 0; n < 4; ++n) acc[m][n] = f32x4{0.f, 0.f, 0.f, 0.f};

  for (int k0 = 0; k0 < K; k0 += BK) {
#pragma unroll
    for (int j = 0; j < 4; ++j) {
      int ci = j * 256 + tid;
      int row = ci >> 3, c8 = (ci & 7) << 3;
      gload_lds16(Ab + (size_t)row * K + (k0 + c8), &As[ci * 8]);
    }
#pragma unroll
    for (int j = 0; j < 4; ++j) {
      int ci = j * 256 + tid;
      int row = ci >> 3, c8 = (ci & 7) << 3;
      gload_lds16(Bb + (size_t)row * K + (k0 + c8), &Bs[ci * 8]);
    }
    __syncthreads();
#pragma unroll
    for (int kk = 0; kk < BK; kk += 32) {
      s16x8 af[4], bfr[4];
#pragma unroll
      for (int m = 0; m < 4; ++m)
        af[m] = *(const s16x8*)&As[(wr * 64 + m * 16 + r) * BK + kk + kg * 8];
#pragma unroll
      for (int n = 0; n < 4; ++n)
        bfr[n] = *(const s16x8*)&Bs[(wc * 64 + n * 16 + r) * BK + kk + kg * 8];
#pragma unroll
      for (int m = 0; m < 4; ++m)
#pragma unroll
        for (int n = 0; n < 4; ++n)
          acc[m][n] = __builtin_amdgcn_mfma_f32_16x16x32_bf16(af[m], bfr[n], acc[m][n], 0, 0, 0);
    }
    __syncthreads();
  }

#pragma unroll
  for (int m = 0; m < 4; ++m) {
#pragma unroll
    for (int n = 0; n < 4; ++n) {
#pragma unroll
      for (int j = 0; j < 4; ++j) {
        int row = bm * BM + wr * 64 + m * 16 + kg * 4 + j;
        int col = bn * BN + wc * 64 + n * 16 + r;
        size_t idx = (size_t)row * N + col;
        float v = acc[m][n][j];
        if constexpr (EPI == 0) {
          ((u16*)Cv)[idx] = f2bf(v);
        } else if constexpr (EPI == 1) {
          ((float*)Cv)[idx] = v + bias[col] + resid[idx];
        } else if constexpr (EPI == 2) {
          ((u16*)Cv)[idx] = f2bf(fmaxf(v + bias[col], 0.f));
        } else {
          ((float*)Cv)[idx] = v + bias[col] + resid[idx];
        }
      }
    }
  }
}

// ---------------- MFMA flash attention: one block per (b,h), 4 waves, wave w = 64 q-rows ----
// qkv [B*T][3072] bf16 (cols: 0..1023 Q | 1024..2047 K | 2048..3071 V, per-head 64 chunks)
// K tile in LDS linear [key][64] with XOR-swizzled source (rule #21); V transposed [d][key] pad 72.
__global__ __launch_bounds__(256)
void attn_mfma(const u16* __restrict__ qkv, u16* __restrict__ outc)
{
  const int bh = blockIdx.x, b = bh >> 4, h = bh & 15;
  const int tid = threadIdx.x;
  const int lane = tid & 63, w = tid >> 6;
  const int r = lane & 15, kg = lane >> 4;

  __shared__ u16 Ks[64 * 64];       // swizzled chunks
  __shared__ u16 Vt[64 * 72];       // [d][key], stride 72 (144B, 16B-aligned)
  __shared__ u16 P[4][64 * 72];     // per-wave P, [qrow][key], stride 72

  const u16* qbase = qkv + (size_t)(b * 256) * 3072 + h * 64;

  // Q fragments (A-layout): rows w*64 + m*16 + r, cols ks*32 + kg*8
  s16x8 qf[4][2];
#pragma unroll
  for (int m = 0; m < 4; ++m)
#pragma unroll
    for (int ks = 0; ks < 2; ++ks)
      qf[m][ks] = *(const s16x8*)(qbase + (size_t)(w * 64 + m * 16 + r) * 3072 + ks * 32 + kg * 8);

  f32x4 of[4][4];
  float mrun[4][4], lrun[4][4];
#pragma unroll
  for (int m = 0; m < 4; ++m) {
#pragma unroll
    for (int n = 0; n < 4; ++n) of[m][n] = f32x4{0.f, 0.f, 0.f, 0.f};
#pragma unroll
    for (int j = 0; j < 4; ++j) { mrun[m][j] = -1e30f; lrun[m][j] = 0.f; }
  }

  const float cexp = 0.03125f * 1.4426950408889634f;  // C^-0.5 * log2(e)

  for (int kt = 0; kt < 4; ++kt) {
    // ---- stage K tile kt: 512 16B chunks, source-swizzled so swizzled read is conflict-free
#pragma unroll
    for (int jj = 0; jj < 2; ++jj) {
      int ci = jj * 256 + tid;
      int key = ci >> 3, seg = ci & 7;
      int sseg = seg ^ (key & 7);
      gload_lds16(qkv + (size_t)(b * 256 + kt * 64 + key) * 3072 + 1024 + h * 64 + sseg * 8,
                  &Ks[ci * 8]);
    }
    // ---- stage V tile kt transposed: thread handles (key=tid>>2, quarter q=tid&3)
    {
      int row = tid >> 2, q = tid & 3;
      const u16* vg = qkv + (size_t)(b * 256 + kt * 64 + row) * 3072 + 2048 + h * 64 + q * 16;
      union { uint4 u[2]; u16 s[16]; } vv;
      vv.u[0] = *(const uint4*)vg;
      vv.u[1] = *(const uint4*)(vg + 8);
#pragma unroll
      for (int i = 0; i < 16; ++i)
        Vt[(q * 16 + i) * 72 + row] = vv.s[i];
    }
    __syncthreads();

    if (w >= kt) {
      // ---- S = Q K^T  (A=Q frags, B=K rows as B^T[N=key][K=d])
      f32x4 s[4][4];
#pragma unroll
      for (int m = 0; m < 4; ++m)
#pragma unroll
        for (int n = 0; n < 4; ++n) s[m][n] = f32x4{0.f, 0.f, 0.f, 0.f};
#pragma unroll
      for (int ks = 0; ks < 2; ++ks) {
        s16x8 kb[4];
#pragma unroll
        for (int n = 0; n < 4; ++n) {
          int row = n * 16 + r;
          int sseg = (ks * 4 + kg) ^ (row & 7);
          kb[n] = *(const s16x8*)&Ks[row * 64 + sseg * 8];
        }
#pragma unroll
        for (int m = 0; m < 4; ++m)
#pragma unroll
          for (int n = 0; n < 4; ++n)
            s[m][n] = __builtin_amdgcn_mfma_f32_16x16x32_bf16(qf[m][ks], kb[n], s[m][n], 0, 0, 0);
      }
      // ---- causal mask on diagonal tile
      if (kt == w) {
#pragma unroll
        for (int m = 0; m < 4; ++m)
#pragma unroll
          for (int n = 0; n < 4; ++n)
#pragma unroll
            for (int j = 0; j < 4; ++j)
              if (n * 16 + r > m * 16 + kg * 4 + j) s[m][n][j] = -1e30f;
      }
      // ---- online softmax (row = kg*4+j lane-replicated after 16-lane reduce)
#pragma unroll
      for (int m = 0; m < 4; ++m) {
        float rm[4], rsc[4], ls[4];
#pragma unroll
        for (int j = 0; j < 4; ++j) {
          rm[j] = fmaxf(fmaxf(s[m][0][j], s[m][1][j]), fmaxf(s[m][2][j], s[m][3][j]));
          rm[j] = fmaxf(rm[j], __shfl_xor(rm[j], 1));
          rm[j] = fmaxf(rm[j], __shfl_xor(rm[j], 2));
          rm[j] = fmaxf(rm[j], __shfl_xor(rm[j], 4));
          rm[j] = fmaxf(rm[j], __shfl_xor(rm[j], 8));
          float mnew = fmaxf(mrun[m][j], rm[j]);
          rsc[j] = exp2f((mrun[m][j] - mnew) * cexp);
          mrun[m][j] = mnew;
          ls[j] = 0.f;
        }
#pragma unroll
        for (int n = 0; n < 4; ++n)
#pragma unroll
          for (int j = 0; j < 4; ++j) {
            float p = exp2f((s[m][n][j] - mrun[m][j]) * cexp);
            ls[j] += p;
            P[w][(m * 16 + kg * 4 + j) * 72 + n * 16 + r] = f2bf(p);
          }
#pragma unroll
        for (int j = 0; j < 4; ++j) {
          ls[j] += __shfl_xor(ls[j], 1);
          ls[j] += __shfl_xor(ls[j], 2);
          ls[j] += __shfl_xor(ls[j], 4);
          ls[j] += __shfl_xor(ls[j], 8);
          lrun[m][j] = lrun[m][j] * rsc[j] + ls[j];
        }
#pragma unroll
        for (int n = 0; n < 4; ++n)
#pragma unroll
          for (int j = 0; j < 4; ++j)
            of[m][n][j] *= rsc[j];
      }
      // ---- O += P V  (A=P from LDS, B=Vt[d][key] as B^T[N=d][K=key])
#pragma unroll
      for (int kk = 0; kk < 2; ++kk) {
        s16x8 pa[4], vb[4];
#pragma unroll
        for (int m = 0; m < 4; ++m)
          pa[m] = *(const s16x8*)&P[w][(m * 16 + r) * 72 + kk * 32 + kg * 8];
#pragma unroll
        for (int n = 0; n < 4; ++n)
          vb[n] = *(const s16x8*)&Vt[(n * 16 + r) * 72 + kk * 32 + kg * 8];
#pragma unroll
        for (int m = 0; m < 4; ++m)
#pragma unroll
          for (int n = 0; n < 4; ++n)
            of[m][n] = __builtin_amdgcn_mfma_f32_16x16x32_bf16(pa[m], vb[n], of[m][n], 0, 0, 0);
      }
    }
    __syncthreads();
  }

  // ---- normalize + write: row = w*64 + m*16 + kg*4 + j, col = h*64 + n*16 + r
#pragma unroll
  for (int m = 0; m < 4; ++m) {
    float inv[4];
#pragma unroll
    for (int j = 0; j < 4; ++j) inv[j] = 1.f / lrun[m][j];
#pragma unroll
    for (int n = 0; n < 4; ++n)
#pragma unroll
      for (int j = 0; j < 4; ++j) {
        int row = b * 256 + w * 64 + m * 16 + kg * 4 + j;
        outc[(size_t)row * 1024 + h * 64 + n * 16 + r] = f2bf(of[m][n][j] * inv[j]);
      }
  }
}

// ------------------------------------------------------------------------------------------
extern "C" void kernel_launch(void* const* d_in, const int* in_sizes, int n_in,
                              void* d_out, int out_size, void* d_ws, size_t ws_size,
                              hipStream_t stream) {
  (void)in_sizes; (void)n_in; (void)out_size; (void)ws_size;
  const float* x     = (const float*)d_in[0];
  const float* Wq    = (const float*)d_in[1];
  const float* Wk    = (const float*)d_in[2];
  const float* Wv    = (const float*)d_in[3];
  const float* Wproj = (const float*)d_in[4];
  const float* bproj = (const float*)d_in[5];
  const float* W1    = (const float*)d_in[6];
  const float* b1    = (const float*)d_in[7];
  const float* W2    = (const float*)d_in[8];
  const float* b2    = (const float*)d_in[9];
  const float* ln1g  = (const float*)d_in[10];
  const float* ln1b  = (const float*)d_in[11];
  const float* ln2g  = (const float*)d_in[12];
  const float* ln2b  = (const float*)d_in[13];
  float* out = (float*)d_out;

  char* ws = (char*)d_ws;
  u16*   WqkvT  = (u16*)(ws + 0);              // [3072][1024] bf16
  u16*   WprojT = (u16*)(ws + 6291456);        // [1024][1024]
  u16*   W1T    = (u16*)(ws + 8388608);        // [4096][1024]
  u16*   W2T    = (u16*)(ws + 16777216);       // [1024][4096]
  u16*   hb     = (u16*)(ws + 25165824);       // [16384][1024] LN1 out; later reused as attnout
  u16*   qkvb   = (u16*)(ws + 58720256);       // [16384][3072]
  float* x2     = (float*)(ws + 159383552);    // [16384][1024] f32
  u16*   h2     = (u16*)(ws + 226492416);      // [16384][1024]
  u16*   ffn1   = (u16*)(ws + 25165824);       // [16384][4096] overlays hb+qkvb (both dead by then)
  u16*   attnout = hb;

  const int M = 16384;

  // weight packs (transpose to [N][K] bf16)
  transpose_pack<<<dim3(32, 2, 16), 256, 0, stream>>>(Wq, WqkvT,           1024, 64, 65536, 65536);
  transpose_pack<<<dim3(32, 2, 16), 256, 0, stream>>>(Wk, WqkvT + 1048576, 1024, 64, 65536, 65536);
  transpose_pack<<<dim3(32, 2, 16), 256, 0, stream>>>(Wv, WqkvT + 2097152, 1024, 64, 65536, 65536);
  transpose_pack<<<dim3(32, 32, 1), 256, 0, stream>>>(Wproj, WprojT, 1024, 1024, 0, 0);
  transpose_pack<<<dim3(32, 128, 1), 256, 0, stream>>>(W1, W1T, 1024, 4096, 0, 0);
  transpose_pack<<<dim3(128, 32, 1), 256, 0, stream>>>(W2, W2T, 4096, 1024, 0, 0);

  // LN1
  ln_f32_bf16<<<M, 256, 0, stream>>>(x, ln1g, ln1b, hb);

  // QKV fused GEMM: [16384,1024] x [3072,1024]^T -> [16384,3072] bf16
  gemm_bt<0><<<dim3(M / 128, 24), 256, 0, stream>>>(hb, WqkvT, qkvb, nullptr, nullptr, M, 3072, 1024);

  // attention -> attnout [16384][1024] bf16 (concat heads)
  attn_mfma<<<1024, 256, 0, stream>>>(qkvb, attnout);

  // proj + bias + residual(x) -> x2 f32
  gemm_bt<1><<<dim3(M / 128, 8), 256, 0, stream>>>(attnout, WprojT, x2, bproj, x, M, 1024, 1024);

  // LN2
  ln_f32_bf16<<<M, 256, 0, stream>>>(x2, ln2g, ln2b, h2);

  // FFN1: relu(h2 @ W1 + b1) -> ffn1 bf16 [16384][4096]
  gemm_bt<2><<<dim3(M / 128, 32), 256, 0, stream>>>(h2, W1T, ffn1, b1, nullptr, M, 4096, 1024);

  // FFN2: ffn1 @ W2 + b2 + x2 -> out f32
  gemm_bt<3><<<dim3(M / 128, 8), 256, 0, stream>>>(ffn1, W2T, out, b2, x2, M, 1024, 4096);
}

// Round 3
// 643.007 us; speedup vs baseline: 1.8608x; 1.3690x over previous
//
#include <hip/hip_runtime.h>
#include <stdint.h>

using u16 = unsigned short;
using u32 = unsigned int;

typedef __attribute__((ext_vector_type(8))) short s16x8;
typedef __attribute__((ext_vector_type(4))) float f32x4;

__device__ __forceinline__ float bflo(u32 u) { u32 t = u << 16; float f; __builtin_memcpy(&f, &t, 4); return f; }
__device__ __forceinline__ float bfhi(u32 u) { u32 t = u & 0xffff0000u; float f; __builtin_memcpy(&f, &t, 4); return f; }
__device__ __forceinline__ u16 f2bf(float f) {
  u32 u; __builtin_memcpy(&u, &f, 4);
  return (u16)((u + 0x7fffu + ((u >> 16) & 1u)) >> 16);
}

__device__ __forceinline__ void gload_lds16(const void* g, void* l) {
  __builtin_amdgcn_global_load_lds((const __attribute__((address_space(1))) void*)g,
                                   (__attribute__((address_space(3))) void*)l, 16, 0, 0);
}

// ---------------- transpose + fp32->bf16 pack: in [R][Cc] -> out [Cc][R] ----------------
__global__ __launch_bounds__(256)
void transpose_pack(const float* __restrict__ in, u16* __restrict__ out,
                    int R, int Cc, long in_bs, long out_bs)
{
  __shared__ float tile[32][33];
  in  += (size_t)blockIdx.z * in_bs;
  out += (size_t)blockIdx.z * out_bs;
  const int r0 = blockIdx.x * 32, c0 = blockIdx.y * 32;
  const int tx = threadIdx.x & 31, ty = threadIdx.x >> 5;   // 32 x 8
#pragma unroll
  for (int i = 0; i < 4; ++i) {
    int r = ty + i * 8;
    tile[r][tx] = in[(size_t)(r0 + r) * Cc + c0 + tx];
  }
  __syncthreads();
#pragma unroll
  for (int i = 0; i < 4; ++i) {
    int c = ty + i * 8;
    out[(size_t)(c0 + c) * R + r0 + tx] = f2bf(tile[tx][c]);
  }
}

// ---------------- LayerNorm fp32 -> bf16, C=1024, one block per row ----------------
__global__ __launch_bounds__(256)
void ln_f32_bf16(const float* __restrict__ x, const float* __restrict__ g,
                 const float* __restrict__ bta, u16* __restrict__ out)
{
  const int row = blockIdx.x, tid = threadIdx.x;
  const float4 v = ((const float4*)(x + (size_t)row * 1024))[tid];
  float s  = v.x + v.y + v.z + v.w;
  float ss = v.x * v.x + v.y * v.y + v.z * v.z + v.w * v.w;
#pragma unroll
  for (int m = 1; m < 64; m <<= 1) {
    s  += __shfl_xor(s, m);
    ss += __shfl_xor(ss, m);
  }
  __shared__ float red[8];
  const int wave = tid >> 6, lane = tid & 63;
  if (lane == 0) { red[wave] = s; red[4 + wave] = ss; }
  __syncthreads();
  s  = red[0] + red[1] + red[2] + red[3];
  ss = red[4] + red[5] + red[6] + red[7];
  const float mu  = s * (1.f / 1024.f);
  const float var = ss * (1.f / 1024.f) - mu * mu;
  const float rs  = rsqrtf(var + 1e-5f);
  const float4 gg = ((const float4*)g)[tid];
  const float4 bb = ((const float4*)bta)[tid];
  u32 w0 = (u32)f2bf((v.x - mu) * rs * gg.x + bb.x) | ((u32)f2bf((v.y - mu) * rs * gg.y + bb.y) << 16);
  u32 w1 = (u32)f2bf((v.z - mu) * rs * gg.z + bb.z) | ((u32)f2bf((v.w - mu) * rs * gg.w + bb.w) << 16);
  u32* outp = (u32*)(out + (size_t)row * 1024 + tid * 4);
  outp[0] = w0; outp[1] = w1;
}

// ---------------- 256x256 8-phase GEMM (T1+T2+T3+T4+T5), A[M][K] bf16, B[N][K] bf16 -------
// LDS: A[2 buf][2 Khalf][256 rows][32 cols] + B same = 128 KiB. Khalf = 32 K-cols.
// 8 waves (2Mx4N), per-wave 128x64 output, acc[8][4] f32x4.
// Phase p of tile t (4 phases, ks-major): ph1 {a m0-3 ks0, b ks0} ph2 {a m4-7 ks0}
// ph3 {a m0-3 ks1, b ks1} ph4 {a m4-7 ks1}. Stages: ph1->t+1.A-kh1, ph2->t+1.B-kh1,
// ph3->t+2.A-kh0 (slot dead after ph2), ph4->t+2.B-kh0 (dead after ph1). vmcnt(4) at ph4.
template <int EPI>
__global__ __launch_bounds__(512, 1)
void gemm8p(const u16* __restrict__ A, const u16* __restrict__ B, void* __restrict__ Cv,
            const float* __restrict__ bias, const float* __restrict__ resid,
            int M, int N, int K, int GM)
{
  __shared__ u16 lds[65536];   // 128 KiB
  const int NT = K >> 6;
  const int tid = threadIdx.x;
  const int lane = tid & 63, wv = tid >> 6;
  const int wr = wv >> 2, wc = wv & 3;            // 2x4 wave grid
  const int r = lane & 15, kg = lane >> 4;

  // XCD-aware bijective swizzle (all grids divisible by 8), bn-major chunks
  const int nwg = gridDim.x;
  const int q = nwg >> 3;
  const int bid = blockIdx.x;
  const int sw = (bid & 7) * q + (bid >> 3);
  const int bn = sw / GM, bm = sw % GM;

  const u16* Ab = A + (size_t)bm * 256 * K;
  const u16* Bb = B + (size_t)bn * 256 * K;

  // swizzled ds_read seg: seg = kg ^ ((row>>1)&3); (row>>1)&3 == (r>>1)&3 for all m,n
  const int segx = (kg ^ ((r >> 1) & 3)) << 3;                // u16 units
  const int aoff = (wr * 128 + r) * 32 + segx;                // + m*512 + kh*8192 + buf*16384
  const int boff = 32768 + (wc * 64 + r) * 32 + segx;         // + n*512 + kh*8192 + buf*16384

  f32x4 acc[8][4];
#pragma unroll
  for (int m = 0; m < 8; ++m)
#pragma unroll
    for (int n = 0; n < 4; ++n) acc[m][n] = f32x4{0.f, 0.f, 0.f, 0.f};

  // stage one half-tile (256 rows x 32 cols, 16 KB) : linear LDS dest, pre-swizzled global src
  auto stage = [&](const u16* src, int u, int kh, int base) {
#pragma unroll
    for (int jj = 0; jj < 2; ++jj) {
      int ci = jj * 512 + tid;
      int row = ci >> 2;
      int sseg = (ci & 3) ^ ((ci >> 3) & 3);
      gload_lds16(src + (size_t)row * K + u * 64 + kh * 32 + sseg * 8, &lds[base + ci * 8]);
    }
  };

  // ---- prologue: t0 all 4 halves -> buf0 ; t1 kh0 halves -> buf1
  stage(Ab, 0, 0, 0);
  stage(Bb, 0, 0, 32768);
  stage(Ab, 0, 1, 8192);
  stage(Bb, 0, 1, 32768 + 8192);
  if (NT > 1) {
    stage(Ab, 1, 0, 16384);
    stage(Bb, 1, 0, 32768 + 16384);
    asm volatile("s_waitcnt vmcnt(4)" ::: "memory");
  } else {
    asm volatile("s_waitcnt vmcnt(0)" ::: "memory");
  }
  __builtin_amdgcn_s_barrier();
  __builtin_amdgcn_sched_barrier(0);

  for (int t = 0; t < NT; ++t) {
    const int buf = t & 1;
    const int ab = buf * 16384;
    const bool s1 = (t + 1) < NT, s2 = (t + 2) < NT;
    s16x8 av[4], bv[4];

    // ---- ph1: ks=0, m=0..3 (+ b ks0)
#pragma unroll
    for (int m = 0; m < 4; ++m) av[m] = *(const s16x8*)&lds[ab + aoff + m * 512];
#pragma unroll
    for (int n = 0; n < 4; ++n) bv[n] = *(const s16x8*)&lds[ab + boff + n * 512];
    if (s1) stage(Ab, t + 1, 1, (buf ^ 1) * 16384 + 8192);
    __builtin_amdgcn_s_barrier();
    __builtin_amdgcn_sched_barrier(0);
    __builtin_amdgcn_s_setprio(1);
#pragma unroll
    for (int m = 0; m < 4; ++m)
#pragma unroll
      for (int n = 0; n < 4; ++n)
        acc[m][n] = __builtin_amdgcn_mfma_f32_16x16x32_bf16(av[m], bv[n], acc[m][n], 0, 0, 0);
    __builtin_amdgcn_s_setprio(0);
    __builtin_amdgcn_sched_barrier(0);
    __builtin_amdgcn_s_barrier();
    __builtin_amdgcn_sched_barrier(0);

    // ---- ph2: ks=0, m=4..7 (bv reused)
#pragma unroll
    for (int m = 0; m < 4; ++m) av[m] = *(const s16x8*)&lds[ab + aoff + (m + 4) * 512];
    if (s1) stage(Bb, t + 1, 1, 32768 + (buf ^ 1) * 16384 + 8192);
    __builtin_amdgcn_s_barrier();
    __builtin_amdgcn_sched_barrier(0);
    __builtin_amdgcn_s_setprio(1);
#pragma unroll
    for (int m = 0; m < 4; ++m)
#pragma unroll
      for (int n = 0; n < 4; ++n)
        acc[m + 4][n] = __builtin_amdgcn_mfma_f32_16x16x32_bf16(av[m], bv[n], acc[m + 4][n], 0, 0, 0);
    __builtin_amdgcn_s_setprio(0);
    __builtin_amdgcn_sched_barrier(0);
    __builtin_amdgcn_s_barrier();
    __builtin_amdgcn_sched_barrier(0);

    // ---- ph3: ks=1, m=0..3 (+ b ks1)
#pragma unroll
    for (int m = 0; m < 4; ++m) av[m] = *(const s16x8*)&lds[ab + aoff + 8192 + m * 512];
#pragma unroll
    for (int n = 0; n < 4; ++n) bv[n] = *(const s16x8*)&lds[ab + boff + 8192 + n * 512];
    if (s2) stage(Ab, t + 2, 0, buf * 16384);
    __builtin_amdgcn_s_barrier();
    __builtin_amdgcn_sched_barrier(0);
    __builtin_amdgcn_s_setprio(1);
#pragma unroll
    for (int m = 0; m < 4; ++m)
#pragma unroll
      for (int n = 0; n < 4; ++n)
        acc[m][n] = __builtin_amdgcn_mfma_f32_16x16x32_bf16(av[m], bv[n], acc[m][n], 0, 0, 0);
    __builtin_amdgcn_s_setprio(0);
    __builtin_amdgcn_sched_barrier(0);
    __builtin_amdgcn_s_barrier();
    __builtin_amdgcn_sched_barrier(0);

    // ---- ph4: ks=1, m=4..7
#pragma unroll
    for (int m = 0; m < 4; ++m) av[m] = *(const s16x8*)&lds[ab + aoff + 8192 + (m + 4) * 512];
    if (s2) stage(Bb, t + 2, 0, 32768 + buf * 16384);
    __builtin_amdgcn_s_barrier();
    __builtin_amdgcn_sched_barrier(0);
    __builtin_amdgcn_s_setprio(1);
#pragma unroll
    for (int m = 0; m < 4; ++m)
#pragma unroll
      for (int n = 0; n < 4; ++n)
        acc[m + 4][n] = __builtin_amdgcn_mfma_f32_16x16x32_bf16(av[m], bv[n], acc[m + 4][n], 0, 0, 0);
    __builtin_amdgcn_s_setprio(0);
    __builtin_amdgcn_sched_barrier(0);
    if (s2) asm volatile("s_waitcnt vmcnt(4)" ::: "memory");
    else    asm volatile("s_waitcnt vmcnt(0)" ::: "memory");
    __builtin_amdgcn_s_barrier();
    __builtin_amdgcn_sched_barrier(0);
  }

  // ---- epilogue
#pragma unroll
  for (int m = 0; m < 8; ++m) {
#pragma unroll
    for (int n = 0; n < 4; ++n) {
#pragma unroll
      for (int j = 0; j < 4; ++j) {
        int row = bm * 256 + wr * 128 + m * 16 + kg * 4 + j;
        int col = bn * 256 + wc * 64 + n * 16 + r;
        size_t idx = (size_t)row * N + col;
        float v = acc[m][n][j];
        if constexpr (EPI == 0) {
          ((u16*)Cv)[idx] = f2bf(v);
        } else if constexpr (EPI == 1) {
          ((float*)Cv)[idx] = v + bias[col] + resid[idx];
        } else if constexpr (EPI == 2) {
          ((u16*)Cv)[idx] = f2bf(fmaxf(v + bias[col], 0.f));
        } else {
          ((float*)Cv)[idx] = v + bias[col] + resid[idx];
        }
      }
    }
  }
}

// ---------------- MFMA flash attention: one block per (b,h), 4 waves, wave w = 64 q-rows ----
__global__ __launch_bounds__(256)
void attn_mfma(const u16* __restrict__ qkv, u16* __restrict__ outc)
{
  const int bh = blockIdx.x, b = bh >> 4, h = bh & 15;
  const int tid = threadIdx.x;
  const int lane = tid & 63, w = tid >> 6;
  const int r = lane & 15, kg = lane >> 4;

  __shared__ u16 Ks[64 * 64];       // swizzled chunks
  __shared__ u16 Vt[64 * 72];       // [d][key], stride 72
  __shared__ u16 P[4][64 * 72];     // per-wave P, [qrow][key], stride 72

  const u16* qbase = qkv + (size_t)(b * 256) * 3072 + h * 64;

  s16x8 qf[4][2];
#pragma unroll
  for (int m = 0; m < 4; ++m)
#pragma unroll
    for (int ks = 0; ks < 2; ++ks)
      qf[m][ks] = *(const s16x8*)(qbase + (size_t)(w * 64 + m * 16 + r) * 3072 + ks * 32 + kg * 8);

  f32x4 of[4][4];
  float mrun[4][4], lrun[4][4];
#pragma unroll
  for (int m = 0; m < 4; ++m) {
#pragma unroll
    for (int n = 0; n < 4; ++n) of[m][n] = f32x4{0.f, 0.f, 0.f, 0.f};
#pragma unroll
    for (int j = 0; j < 4; ++j) { mrun[m][j] = -1e30f; lrun[m][j] = 0.f; }
  }

  const float cexp = 0.03125f * 1.4426950408889634f;

  for (int kt = 0; kt < 4; ++kt) {
#pragma unroll
    for (int jj = 0; jj < 2; ++jj) {
      int ci = jj * 256 + tid;
      int key = ci >> 3, seg = ci & 7;
      int sseg = seg ^ (key & 7);
      gload_lds16(qkv + (size_t)(b * 256 + kt * 64 + key) * 3072 + 1024 + h * 64 + sseg * 8,
                  &Ks[ci * 8]);
    }
    {
      int row = tid >> 2, q = tid & 3;
      const u16* vg = qkv + (size_t)(b * 256 + kt * 64 + row) * 3072 + 2048 + h * 64 + q * 16;
      union { uint4 u[2]; u16 s[16]; } vv;
      vv.u[0] = *(const uint4*)vg;
      vv.u[1] = *(const uint4*)(vg + 8);
#pragma unroll
      for (int i = 0; i < 16; ++i)
        Vt[(q * 16 + i) * 72 + row] = vv.s[i];
    }
    __syncthreads();

    if (w >= kt) {
      f32x4 s[4][4];
#pragma unroll
      for (int m = 0; m < 4; ++m)
#pragma unroll
        for (int n = 0; n < 4; ++n) s[m][n] = f32x4{0.f, 0.f, 0.f, 0.f};
#pragma unroll
      for (int ks = 0; ks < 2; ++ks) {
        s16x8 kb[4];
#pragma unroll
        for (int n = 0; n < 4; ++n) {
          int row = n * 16 + r;
          int sseg = (ks * 4 + kg) ^ (row & 7);
          kb[n] = *(const s16x8*)&Ks[row * 64 + sseg * 8];
        }
#pragma unroll
        for (int m = 0; m < 4; ++m)
#pragma unroll
          for (int n = 0; n < 4; ++n)
            s[m][n] = __builtin_amdgcn_mfma_f32_16x16x32_bf16(qf[m][ks], kb[n], s[m][n], 0, 0, 0);
      }
      if (kt == w) {
#pragma unroll
        for (int m = 0; m < 4; ++m)
#pragma unroll
          for (int n = 0; n < 4; ++n)
#pragma unroll
            for (int j = 0; j < 4; ++j)
              if (n * 16 + r > m * 16 + kg * 4 + j) s[m][n][j] = -1e30f;
      }
#pragma unroll
      for (int m = 0; m < 4; ++m) {
        float rm[4], rsc[4], ls[4];
#pragma unroll
        for (int j = 0; j < 4; ++j) {
          rm[j] = fmaxf(fmaxf(s[m][0][j], s[m][1][j]), fmaxf(s[m][2][j], s[m][3][j]));
          rm[j] = fmaxf(rm[j], __shfl_xor(rm[j], 1));
          rm[j] = fmaxf(rm[j], __shfl_xor(rm[j], 2));
          rm[j] = fmaxf(rm[j], __shfl_xor(rm[j], 4));
          rm[j] = fmaxf(rm[j], __shfl_xor(rm[j], 8));
          float mnew = fmaxf(mrun[m][j], rm[j]);
          rsc[j] = exp2f((mrun[m][j] - mnew) * cexp);
          mrun[m][j] = mnew;
          ls[j] = 0.f;
        }
#pragma unroll
        for (int n = 0; n < 4; ++n)
#pragma unroll
          for (int j = 0; j < 4; ++j) {
            float p = exp2f((s[m][n][j] - mrun[m][j]) * cexp);
            ls[j] += p;
            P[w][(m * 16 + kg * 4 + j) * 72 + n * 16 + r] = f2bf(p);
          }
#pragma unroll
        for (int j = 0; j < 4; ++j) {
          ls[j] += __shfl_xor(ls[j], 1);
          ls[j] += __shfl_xor(ls[j], 2);
          ls[j] += __shfl_xor(ls[j], 4);
          ls[j] += __shfl_xor(ls[j], 8);
          lrun[m][j] = lrun[m][j] * rsc[j] + ls[j];
        }
#pragma unroll
        for (int n = 0; n < 4; ++n)
#pragma unroll
          for (int j = 0; j < 4; ++j)
            of[m][n][j] *= rsc[j];
      }
#pragma unroll
      for (int kk = 0; kk < 2; ++kk) {
        s16x8 pa[4], vb[4];
#pragma unroll
        for (int m = 0; m < 4; ++m)
          pa[m] = *(const s16x8*)&P[w][(m * 16 + r) * 72 + kk * 32 + kg * 8];
#pragma unroll
        for (int n = 0; n < 4; ++n)
          vb[n] = *(const s16x8*)&Vt[(n * 16 + r) * 72 + kk * 32 + kg * 8];
#pragma unroll
        for (int m = 0; m < 4; ++m)
#pragma unroll
          for (int n = 0; n < 4; ++n)
            of[m][n] = __builtin_amdgcn_mfma_f32_16x16x32_bf16(pa[m], vb[n], of[m][n], 0, 0, 0);
      }
    }
    __syncthreads();
  }

#pragma unroll
  for (int m = 0; m < 4; ++m) {
    float inv[4];
#pragma unroll
    for (int j = 0; j < 4; ++j) inv[j] = 1.f / lrun[m][j];
#pragma unroll
    for (int n = 0; n < 4; ++n)
#pragma unroll
      for (int j = 0; j < 4; ++j) {
        int row = b * 256 + w * 64 + m * 16 + kg * 4 + j;
        outc[(size_t)row * 1024 + h * 64 + n * 16 + r] = f2bf(of[m][n][j] * inv[j]);
      }
  }
}

// ------------------------------------------------------------------------------------------
extern "C" void kernel_launch(void* const* d_in, const int* in_sizes, int n_in,
                              void* d_out, int out_size, void* d_ws, size_t ws_size,
                              hipStream_t stream) {
  (void)in_sizes; (void)n_in; (void)out_size; (void)ws_size;
  const float* x     = (const float*)d_in[0];
  const float* Wq    = (const float*)d_in[1];
  const float* Wk    = (const float*)d_in[2];
  const float* Wv    = (const float*)d_in[3];
  const float* Wproj = (const float*)d_in[4];
  const float* bproj = (const float*)d_in[5];
  const float* W1    = (const float*)d_in[6];
  const float* b1    = (const float*)d_in[7];
  const float* W2    = (const float*)d_in[8];
  const float* b2    = (const float*)d_in[9];
  const float* ln1g  = (const float*)d_in[10];
  const float* ln1b  = (const float*)d_in[11];
  const float* ln2g  = (const float*)d_in[12];
  const float* ln2b  = (const float*)d_in[13];
  float* out = (float*)d_out;

  char* ws = (char*)d_ws;
  u16*   WqkvT  = (u16*)(ws + 0);              // [3072][1024] bf16
  u16*   WprojT = (u16*)(ws + 6291456);        // [1024][1024]
  u16*   W1T    = (u16*)(ws + 8388608);        // [4096][1024]
  u16*   W2T    = (u16*)(ws + 16777216);       // [1024][4096]
  u16*   hb     = (u16*)(ws + 25165824);       // [16384][1024] LN1 out; later reused as attnout
  u16*   qkvb   = (u16*)(ws + 58720256);       // [16384][3072]
  float* x2     = (float*)(ws + 159383552);    // [16384][1024] f32
  u16*   h2     = (u16*)(ws + 226492416);      // [16384][1024]
  u16*   ffn1   = (u16*)(ws + 25165824);       // [16384][4096] overlays hb+qkvb (both dead by then)
  u16*   attnout = hb;

  const int M = 16384;

  transpose_pack<<<dim3(32, 2, 16), 256, 0, stream>>>(Wq, WqkvT,           1024, 64, 65536, 65536);
  transpose_pack<<<dim3(32, 2, 16), 256, 0, stream>>>(Wk, WqkvT + 1048576, 1024, 64, 65536, 65536);
  transpose_pack<<<dim3(32, 2, 16), 256, 0, stream>>>(Wv, WqkvT + 2097152, 1024, 64, 65536, 65536);
  transpose_pack<<<dim3(32, 32, 1), 256, 0, stream>>>(Wproj, WprojT, 1024, 1024, 0, 0);
  transpose_pack<<<dim3(32, 128, 1), 256, 0, stream>>>(W1, W1T, 1024, 4096, 0, 0);
  transpose_pack<<<dim3(128, 32, 1), 256, 0, stream>>>(W2, W2T, 4096, 1024, 0, 0);

  ln_f32_bf16<<<M, 256, 0, stream>>>(x, ln1g, ln1b, hb);

  // QKV: [16384,1024] x [3072,1024]^T -> bf16 ; grid = GM*GN = 64*12
  gemm8p<0><<<64 * 12, 512, 0, stream>>>(hb, WqkvT, qkvb, nullptr, nullptr, M, 3072, 1024, 64);

  attn_mfma<<<1024, 256, 0, stream>>>(qkvb, attnout);

  // proj + bias + residual(x) -> x2 f32 ; grid 64*4
  gemm8p<1><<<64 * 4, 512, 0, stream>>>(attnout, WprojT, x2, bproj, x, M, 1024, 1024, 64);

  ln_f32_bf16<<<M, 256, 0, stream>>>(x2, ln2g, ln2b, h2);

  // FFN1: relu(h2 @ W1 + b1) -> bf16 ; grid 64*16
  gemm8p<2><<<64 * 16, 512, 0, stream>>>(h2, W1T, ffn1, b1, nullptr, M, 4096, 1024, 64);

  // FFN2: ffn1 @ W2 + b2 + x2 -> out f32 ; grid 64*4
  gemm8p<3><<<64 * 4, 512, 0, stream>>>(ffn1, W2T, out, b2, x2, M, 1024, 4096, 64);
}